// Round 15
// baseline (24.439 us; speedup 1.0000x reference)
//
#include <hip/hip_runtime.h>

// Problem constants
#define NB 64
#define NL 128
#define NQ 128
#define NE 16384

// ws float layout
#define WS_TW    0          // total weight (written by prep oct-0 block)
#define WS_PART  8          // 256 per-block numerator partials (ends 264)
// ws ushort layout (bf16 operand arrays), offsets in ushorts from ws base
#define US_WB    544                     // [i][j]  W bf16 (byte 1088, 16B aligned)
#define US_ATB   (US_WB + 16384)         // [q][p]  A^T bf16
#define US_PB    (US_ATB + 16384)        // [b][i][k] P bf16 plain
#define US_PTB   (US_PB + NB * 16384)    // [b][q][j] P bf16 transposed

using short8 = __attribute__((ext_vector_type(8))) short;  // 8 bf16
using f32x4  = __attribute__((ext_vector_type(4))) float;

// fp32 -> bf16 bits, round-to-nearest-even
__device__ inline unsigned short f2bf(float f) {
    const unsigned u = __float_as_uint(f);
    return (unsigned short)((u + 0x7fffu + ((u >> 16) & 1u)) >> 16);
}

// ---------------------------------------------------------------------------
// prep: 80 blocks x 512 threads.
//  blk 0-63 : b = blk. PB[b] bf16 plain + PTB[b] bf16 transposed (LDS tile).
//  blk 64-71: oct = blk-64. W rows [oct*16,+16): scan all edges, filtered LDS
//             scatter [16][132] fp32, emit bf16 -> WB. oct 0 also writes TW.
//  blk 72-79: ATB[q][p] = bf16 A_fid[p][q] (coalesced reads, 2B transposed
//             stores), 2048 elems per block.
// ---------------------------------------------------------------------------
__global__ __launch_bounds__(512) void prep_kernel(const float* __restrict__ P,
                                                   const float* __restrict__ dhw,
                                                   const float* __restrict__ derr,
                                                   const int*  __restrict__ pairs,
                                                   const float* __restrict__ wts,
                                                   float* __restrict__ ws) {
    const int t = threadIdx.x, blk = blockIdx.x;
    unsigned short* us = (unsigned short*)ws;

    if (blk < 64) {
        const float* __restrict__ Pb = P + blk * 16384;
        unsigned short* __restrict__ PBb  = us + US_PB  + blk * 16384;
        unsigned short* __restrict__ PTBb = us + US_PTB + blk * 16384;
        __shared__ unsigned short T[128 * 132];        // padded transpose tile

        #pragma unroll
        for (int r = 0; r < 8; ++r) {
            const int f = t + 512 * r;                 // float4 idx [0,4096)
            const float4 v = ((const float4*)Pb)[f];
            ushort4 u;
            u.x = f2bf(v.x); u.y = f2bf(v.y); u.z = f2bf(v.z); u.w = f2bf(v.w);
            ((ushort4*)PBb)[f] = u;                    // coalesced 8B stores
            const int i = f >> 5, c = (f & 31) * 4;
            *(ushort4*)&T[i * 132 + c] = u;
        }
        __syncthreads();
        #pragma unroll
        for (int r = 0; r < 4; ++r) {
            const int o  = t + 512 * r;                // short8 idx [0,2048)
            const int q  = o & 127;
            const int j0 = (o >> 7) * 8;
            short8 rd;
            #pragma unroll
            for (int d = 0; d < 8; ++d)
                rd[d] = (short)T[(j0 + d) * 132 + q];
            *(short8*)&PTBb[q * 128 + j0] = rd;
        }
    } else if (blk < 72) {
        __shared__ float Wl[16 * 132];
        __shared__ float red[8];
        const int oct = blk - 64;                      // i-rows [oct*16,+16)
        for (int idx = t; idx < 16 * 132; idx += 512) Wl[idx] = 0.f;
        __syncthreads();

        float tw = 0.f;
        #pragma unroll 4
        for (int r = 0; r < 32; ++r) {
            const int e = t + 512 * r;                 // [0, 16384)
            const int2  pr = ((const int2*)pairs)[e];
            const float w  = wts[e];
            tw += w;
            if ((pr.x >> 4) == oct)
                atomicAdd(&Wl[(pr.x & 15) * 132 + pr.y], w);
        }
        __syncthreads();

        #pragma unroll
        for (int r = 0; r < 4; ++r) {
            const int idx = t + 512 * r;               // [0, 2048)
            const int row = idx >> 7, col = idx & 127;
            us[US_WB + oct * 2048 + idx] = f2bf(Wl[row * 132 + col]);
        }

        if (oct == 0) {
            #pragma unroll
            for (int off = 32; off; off >>= 1) tw += __shfl_down(tw, off, 64);
            if ((t & 63) == 0) red[t >> 6] = tw;
            __syncthreads();
            if (t == 0) {
                float s = 0.f;
                #pragma unroll
                for (int k = 0; k < 8; ++k) s += red[k];
                ws[WS_TW] = s;
            }
        }
    } else {
        #pragma unroll
        for (int r = 0; r < 4; ++r) {
            const int idx = (blk - 72) * 2048 + t + 512 * r;   // [0, 16384)
            const float hw = dhw[idx], er = derr[idx];
            const float a  = (hw == 1.0f) ? fmaxf(1.0f - er, 0.f) : 0.f;
            const int p = idx >> 7, q = idx & 127;
            us[US_ATB + q * 128 + p] = f2bf(a);
        }
    }
}

// ---------------------------------------------------------------------------
// main: 256 blocks x 512 threads; NO LDS staging, NO barriers before reduce.
// block = (b = blk>>2, qtr = blk&3); units uu=0,1 -> i-tile it = qtr*2+uu.
// wave wv = q-tile. All operands contiguous bf16 short8 from L2:
//   accG = sum_k mfma(wa=WB[mrow], gb=PTB[b][ncol])   (G = W P_b)
//   accY = sum_k mfma(pa=PB[b][mrow], yb=ATB[ncol])   (Y = P_b A)
//   s += <accG, accY>   (C-layout invariant elementwise dot)
// ---------------------------------------------------------------------------
__global__ __launch_bounds__(512) void main_kernel(const float* __restrict__ ws_c,
                                                   float* __restrict__ ws) {
    __shared__ float redS[8];
    const int t   = threadIdx.x;
    const int blk = blockIdx.x;                // [0,256)
    const int b   = blk >> 2;
    const int qtr = blk & 3;
    const unsigned short* us = (const unsigned short*)ws_c;
    const unsigned short* __restrict__ PBb  = us + US_PB  + b * 16384;
    const unsigned short* __restrict__ PTBb = us + US_PTB + b * 16384;
    const unsigned short* __restrict__ ATB  = us + US_ATB;
    const unsigned short* __restrict__ WB   = us + US_WB;

    const int wv   = t >> 6;                   // wave -> q-tile
    const int lane = t & 63;
    const int l15  = lane & 15;
    const int kb   = (lane >> 4) * 8;
    const int ncol = wv * 16 + l15;

    // hoisted unit-invariant B-frags (8 contiguous short8 loads)
    short8 gb8[4], yb8[4];
    #pragma unroll
    for (int kk = 0; kk < 4; ++kk) {
        const int k0 = kk * 32 + kb;
        gb8[kk] = *(const short8*)&PTBb[ncol * 128 + k0];
        yb8[kk] = *(const short8*)&ATB[ncol * 128 + k0];
    }

    float s = 0.f;
    #pragma unroll
    for (int uu = 0; uu < 2; ++uu) {
        const int mrow = (qtr * 2 + uu) * 16 + l15;    // global i row
        f32x4 accG = {0.f, 0.f, 0.f, 0.f};
        f32x4 accY = {0.f, 0.f, 0.f, 0.f};
        #pragma unroll
        for (int kk = 0; kk < 4; ++kk) {
            const int k0 = kk * 32 + kb;
            const short8 wa = *(const short8*)&WB[mrow * 128 + k0];
            const short8 pa = *(const short8*)&PBb[mrow * 128 + k0];
            accG = __builtin_amdgcn_mfma_f32_16x16x32_bf16(wa, gb8[kk], accG, 0, 0, 0);
            accY = __builtin_amdgcn_mfma_f32_16x16x32_bf16(pa, yb8[kk], accY, 0, 0, 0);
        }
        s += accG[0] * accY[0] + accG[1] * accY[1]
           + accG[2] * accY[2] + accG[3] * accY[3];
    }

    #pragma unroll
    for (int off = 32; off; off >>= 1) s += __shfl_down(s, off, 64);
    if (lane == 0) redS[wv] = s;
    __syncthreads();
    if (t == 0) {
        float ss = 0.f;
        #pragma unroll
        for (int k = 0; k < 8; ++k) ss += redS[k];
        ws[WS_PART + blk] = ss;                // distinct slot, no atomics
    }
}

// ---------------------------------------------------------------------------
// finalize: 1 block x 256 threads; loss = -(sum(part)/B)/max(tw,1e-8)
// ---------------------------------------------------------------------------
__global__ __launch_bounds__(256) void finalize_kernel(const float* __restrict__ ws,
                                                       float* __restrict__ out) {
    const int t = threadIdx.x, lane = t & 63, wv = t >> 6;
    float n = ws[WS_PART + t];
    #pragma unroll
    for (int off = 32; off; off >>= 1) n += __shfl_down(n, off, 64);
    __shared__ float red[4];
    if (lane == 0) red[wv] = n;
    __syncthreads();
    if (t == 0) {
        const float num = red[0] + red[1] + red[2] + red[3];
        out[0] = -num / ((float)NB * fmaxf(ws[WS_TW], 1e-8f));
    }
}

extern "C" void kernel_launch(void* const* d_in, const int* in_sizes, int n_in,
                              void* d_out, int out_size, void* d_ws, size_t ws_size,
                              hipStream_t stream) {
    const float* P    = (const float*)d_in[0];
    const float* dhw  = (const float*)d_in[1];
    const float* derr = (const float*)d_in[2];
    const int*   prs  = (const int*)d_in[3];
    const float* wts  = (const float*)d_in[4];
    float* ws  = (float*)d_ws;
    float* out = (float*)d_out;

    prep_kernel<<<80, 512, 0, stream>>>(P, dhw, derr, prs, wts, ws);
    main_kernel<<<256, 512, 0, stream>>>(ws, ws);
    finalize_kernel<<<1, 256, 0, stream>>>(ws, out);
}